// Round 11
// baseline (103.299 us; speedup 1.0000x reference)
//
#include <hip/hip_runtime.h>
#include <hip/hip_bf16.h>
#include <math.h>

// CrossGeometricStructureEmbedding, round 18.
// R17 post-mortem: null (bench 101 vs 100; kernel ~30us). Occupancy was the
// wrong lever: the LDS read pipe is per-CU (17.6us busy of ~30), and extra
// co-resident blocks share it. R18 halves the traffic instead - the lever
// that delivered R12/R13/R16. Traffic identity: reads/pt = (256/colwidth)x14.
// Wave widens to 64 cols x all 64 anchors (sequential hh halves, in-wave
// merge), block processes 2 points/phase (waves 0-3 -> pt 2q, 4-7 -> 2q+1).
// 56 KB/pt (half of R17), LDS pipe floor 8.8us/CU. Register envelope ==
// R13's proven spill-free set under the same (512,4)=128 cap: bw[2][7]=56 +
// acc[2]=32 + dm 8 + temps ~110. LDS: E[2buf][2pg][16KB]=64KB + xs 4KB ->
// 2 blocks/CU, 16 waves/CU (R16's occupancy at half the traffic). Fill
// schedule re-derived for 4-wave groups: w4 fills chunks {w4,+4,+8,+12 if
// w4<2}; factor 10^(-(w4+4c)/8); augmented chunk 13 = (w4==1,c==3).
// Swizzle/fragment/epilogue maps verbatim from R13/R16.
// Predict: conflicts 3.67M -> 1.835M (signature), WRITE_SIZE 4096 (gate,
// read first; fallback R16), kernel ~20-24us, bench ~90-95, absmax 0.015625.

typedef __attribute__((ext_vector_type(8))) short short8;
typedef __attribute__((ext_vector_type(16))) float f32x16;
typedef __attribute__((ext_vector_type(4))) unsigned int uint4v;
typedef __attribute__((ext_vector_type(4))) float float4v;
typedef __attribute__((ext_vector_type(4))) unsigned short ushort4v;

#define HH 256
#define KK 112
#define P_PTS 8
#define NPTS 4096

__device__ __forceinline__ unsigned short f2bf(float f) {
    union { float f; unsigned int u; } v; v.f = f;
    unsigned int r = v.u + 0x7fffu + ((v.u >> 16) & 1u);  // RNE
    return (unsigned short)(r >> 16);
}

__device__ __forceinline__ unsigned int pack_sc(float s, float c) {
    union { __hip_bfloat162 h; unsigned int u; } v;
    v.h = __float22bfloat162_rn(make_float2(s, c));  // low = even elem, high = odd
    return v.u;
}

// Build trimmed+augmented W: wbf[(t*256+o)*112 + e]
//   e in [0,104): W[o][e] bf16 (pairs 0..51)
//   e=104..108: u1 (x), u2 (x^2), u3 (x^3), u4 (x^4), v (1); [109,112): 0
// sin(z) ~ z - z^3/6, cos(z) ~ 1 - z^2/2 + z^4/24 for z = x*d_i, i >= 52.
__global__ __launch_bounds__(64)
void prep_w_kernel(const float* __restrict__ Wa, const float* __restrict__ Wd,
                   unsigned short* __restrict__ wbf) {
    const int r = blockIdx.x * 64 + threadIdx.x;  // 0..511
    const int t = r >> 8, o = r & 255;
    const float* W = (t == 0 ? Wd : Wa) + o * HH;
    unsigned short* dst = wbf + (t * HH + o) * KK;
    #pragma unroll
    for (int e4 = 0; e4 < 26; ++e4) {  // 104 elems as float4
        const float4v w4 = *(const float4v*)(W + e4 * 4);
        ushort4v s4;
        #pragma unroll
        for (int j = 0; j < 4; ++j) s4[j] = f2bf(w4[j]);
        *(ushort4v*)(dst + e4 * 4) = s4;
    }
    float u1 = 0.f, u2 = 0.f, u3 = 0.f, u4 = 0.f, v = 0.f;
    float d = 0.023713737056616554f;  // 10^(-52/32)
    for (int i = 52; i < 128; ++i) {
        const float d2 = d * d;
        const float ws = W[2 * i], wc = W[2 * i + 1];
        u1 += d * ws;
        u3 += -(d * d2) * (1.0f / 6.0f) * ws;
        u2 += -0.5f * d2 * wc;
        u4 += (d2 * d2) * (1.0f / 24.0f) * wc;
        v  += wc;
        d *= 0.9305720409297085f;  // 10^(-1/32)
    }
    dst[104] = f2bf(u1);
    dst[105] = f2bf(u2);
    dst[106] = f2bf(u3);
    dst[107] = f2bf(u4);
    dst[108] = f2bf(v);
    dst[109] = 0; dst[110] = 0; dst[111] = 0;
}

// E swizzle (R13-verified): row stride 256B; 16B chunk ch of row r at byte
//   r*256 + ((ch ^ (r&7)) << 4)  ==  (r<<8) ^ ((r&7)<<4) ^ (ch<<4).
// chunk = w4 + 4c (disjoint bits) -> ch<<4 = (w4<<4) ^ (c<<6).

__global__ __launch_bounds__(512, 4)
void cgse_main(const float* __restrict__ points,
               const float* __restrict__ anchors,
               const unsigned short* __restrict__ wbf,
               const float* __restrict__ ba,
               const float* __restrict__ bd,
               float* __restrict__ out) {
    __shared__ __align__(16) unsigned short E[2][2][64 * 128];  // [buf][pg] 64 KB
    __shared__ float xs[2][P_PTS][64];                          // 4 KB
    __shared__ float anch[192];

    const int tid = threadIdx.x;
    const int wave = tid >> 6, lane = tid & 63;
    const int l5 = lane & 31, half = lane >> 5;
    const int base = blockIdx.x * P_PTS;
    const int pg = wave >> 2;   // point-parity group: waves 0-3 -> pt 2q, 4-7 -> 2q+1
    const int w4 = wave & 3;    // wave's 64-col group within the point

    // ---- anchors, then geometry: 8 pts x 64 anchors = 512 tasks / 512 thr
    if (tid < 192) anch[tid] = anchors[tid];
    __syncthreads();
    {
        const int k2 = (lane + 1) & 63;
        const int pn = base + wave;
        const float px = points[pn * 3 + 0], py = points[pn * 3 + 1], pz = points[pn * 3 + 2];
        const float r1x = px - anch[lane * 3 + 0];
        const float r1y = py - anch[lane * 3 + 1];
        const float r1z = pz - anch[lane * 3 + 2];
        const float r2x = px - anch[k2 * 3 + 0];
        const float r2y = py - anch[k2 * 3 + 1];
        const float r2z = pz - anch[k2 * 3 + 2];
        xs[0][wave][lane] = sqrtf(r1x * r1x + r1y * r1y + r1z * r1z) * 5.0f;  // /SIGMA_D
        const float cx = r1y * r2z - r1z * r2y;
        const float cy = r1z * r2x - r1x * r2z;
        const float cz = r1x * r2y - r1y * r2x;
        const float sv = sqrtf(cx * cx + cy * cy + cz * cz);
        const float cv = r1x * r2x + r1y * r2y + r1z * r2z;
        xs[1][wave][lane] = atan2f(sv, cv) * 3.8197186342054885f;  // *180/(15*pi)
    }

    float bias[2];
    #pragma unroll
    for (int ntp = 0; ntp < 2; ++ntp) {
        const int c = w4 * 64 + ntp * 32 + l5;
        bias[ntp] = ba[c] + bd[c];
    }

    // fill constants: within its point-group, wave w4 fills chunks
    // {w4, w4+4, w4+8, w4+12 (w4<2)}; chunk ch = w4+4c covers pairs 4ch..4ch+3,
    // factor 10^(-ch/8) = 10^(-w4/8) * 10^(-c/2). Augmented chunk 13: w4=1,c=3.
    const float cw = 0.15915494309189535f * __expf(-(float)w4 * 0.2878231366242554f);

    // XOR-decomposed address bases (bytes), within the pg tile
    const int tb = pg * 16384;                                   // tile base
    const int wbase = (lane << 8) ^ (((lane & 7) ^ w4) << 4);    // fill: ^ (c<<6)
    const int rbase = (l5 << 8) ^ ((l5 & 7) << 4) ^ (half << 4); // ^ (ks<<5), +hh*8192

    // fill one 16B chunk: row = lane, chunk = w4 + 4c (c compile-time).
    auto fill_chunk = [&](char* eb, int c, float x, float xc) {
        uint4v w;
        if (w4 == 1 && c == 3) {              // chunk 13: [x,x^2,x^3,x^4,1,0,0,0]
            const float x2 = x * x;
            w[0] = pack_sc(x, x2);
            w[1] = pack_sc(x2 * x, x2 * x2);
            w[2] = pack_sc(1.0f, 0.0f);
            w[3] = 0u;
        } else {
            const float DCI[4] = {1.0f, 0.31622776601683794f, 0.1f,
                                  0.03162277660168379f};       // 10^(-c/2)
            const float t0 = xc * DCI[c];
            const float t[4] = {t0, t0 * 0.9305720409297085f,
                                t0 * 0.8659643233600653f, t0 * 0.8058421877614819f};
            #pragma unroll
            for (int j = 0; j < 4; ++j)
                w[j] = pack_sc(__builtin_amdgcn_sinf(t[j]), __builtin_amdgcn_cosf(t[j]));
        }
        *(uint4v*)(eb + (wbase ^ (c << 6)));
        *(uint4v*)(eb + (wbase ^ (c << 6))) = w;
    };

    // fill this wave's share of its pg tile (3 or 4 chunks)
    auto fill_tile = [&](char* eb, float x) {
        const float xc = x * cw;
        fill_chunk(eb, 0, x, xc);
        fill_chunk(eb, 1, x, xc);
        fill_chunk(eb, 2, x, xc);
        if (w4 < 2) fill_chunk(eb, 3, x, xc);
    };

    // ---- W strips for the wave's 2 col-tiles: 2 x 7 x short8 = 56 VGPRs
    short8 bw[2][7];
    auto loadW = [&](int t) {
        #pragma unroll
        for (int ntp = 0; ntp < 2; ++ntp) {
            const unsigned short* wr =
                wbf + (t * HH + w4 * 64 + ntp * 32 + l5) * KK + half * 8;
            #pragma unroll
            for (int ks = 0; ks < 7; ++ks)
                bw[ntp][ks] = *(const short8*)(wr + ks * 16);
        }
    };

    // max over one anchor-half: 16 acc regs -> scalar (max3-shaped tree)
    auto htree = [&](const f32x16& a) -> float {
        const float v0 = fmaxf(fmaxf(a[0], a[1]), a[2]);
        const float v1 = fmaxf(fmaxf(a[3], a[4]), a[5]);
        const float v2 = fmaxf(fmaxf(a[6], a[7]), a[8]);
        const float v3 = fmaxf(fmaxf(a[9], a[10]), a[11]);
        const float v4 = fmaxf(fmaxf(a[12], a[13]), a[14]);
        const float w0 = fmaxf(fmaxf(v0, v1), v2);
        const float w1 = fmaxf(fmaxf(v3, v4), a[15]);
        return fmaxf(w0, w1);
    };

    loadW(0);
    __syncthreads();  // xs ready
    // prologue: fill buf0/pg for phase 0 (points 0,1; this wave: point pg)
    fill_tile((char*)E[0][pg], xs[0][pg][lane]);

    float dm[4][2];  // d-pass maxes (statically indexed; loops fully unrolled)

    // ---- d-pass: phases 0..3, phase q = points {2q, 2q+1}, wave's pt = 2q+pg
    #pragma unroll
    for (int q = 0; q < 4; ++q) {
        __syncthreads();  // E[q&1] filled; E[q&1^1] free
        const char* ebC = (const char*)E[q & 1][pg];
        char* ebN = (char*)E[(q & 1) ^ 1][pg];
        // fill next (temps die before acc goes live):
        // q<3 -> d-type pt 2(q+1)+pg; q=3 -> a-type pt pg
        fill_tile(ebN, (q < 3) ? xs[0][2 * (q + 1) + pg][lane] : xs[1][pg][lane]);

        float m[2];
        #pragma unroll
        for (int hh = 0; hh < 2; ++hh) {
            f32x16 acc[2];
            #pragma unroll
            for (int ntp = 0; ntp < 2; ++ntp)
                #pragma unroll
                for (int r = 0; r < 16; ++r) acc[ntp][r] = 0.f;
            #pragma unroll
            for (int ks = 0; ks < 7; ++ks) {
                const short8 afr = *(const short8*)
                    (ebC + ((rbase ^ (ks << 5)) + hh * 8192));
                __builtin_amdgcn_s_setprio(1);
                acc[0] = __builtin_amdgcn_mfma_f32_32x32x16_bf16(afr, bw[0][ks], acc[0], 0, 0, 0);
                acc[1] = __builtin_amdgcn_mfma_f32_32x32x16_bf16(afr, bw[1][ks], acc[1], 0, 0, 0);
                __builtin_amdgcn_s_setprio(0);
            }
            #pragma unroll
            for (int ntp = 0; ntp < 2; ++ntp) {
                const float h = htree(acc[ntp]);
                m[ntp] = hh ? fmaxf(m[ntp], h) : h;
            }
        }
        #pragma unroll
        for (int ntp = 0; ntp < 2; ++ntp) {
            m[ntp] = fmaxf(m[ntp], __shfl_down(m[ntp], 32));
            dm[q][ntp] = m[ntp];  // valid on lanes 0..31
        }
    }

    loadW(1);  // Wa; one-time L2 hit, retires at next barrier

    // ---- a-pass: phases 0..3, wave's pt = 2q+pg, writes out directly
    #pragma unroll
    for (int q = 0; q < 4; ++q) {
        __syncthreads();
        const char* ebC = (const char*)E[q & 1][pg];
        char* ebN = (char*)E[(q & 1) ^ 1][pg];
        if (q < 3) fill_tile(ebN, xs[1][2 * (q + 1) + pg][lane]);

        float m[2];
        #pragma unroll
        for (int hh = 0; hh < 2; ++hh) {
            f32x16 acc[2];
            #pragma unroll
            for (int ntp = 0; ntp < 2; ++ntp)
                #pragma unroll
                for (int r = 0; r < 16; ++r) acc[ntp][r] = 0.f;
            #pragma unroll
            for (int ks = 0; ks < 7; ++ks) {
                const short8 afr = *(const short8*)
                    (ebC + ((rbase ^ (ks << 5)) + hh * 8192));
                __builtin_amdgcn_s_setprio(1);
                acc[0] = __builtin_amdgcn_mfma_f32_32x32x16_bf16(afr, bw[0][ks], acc[0], 0, 0, 0);
                acc[1] = __builtin_amdgcn_mfma_f32_32x32x16_bf16(afr, bw[1][ks], acc[1], 0, 0, 0);
                __builtin_amdgcn_s_setprio(0);
            }
            #pragma unroll
            for (int ntp = 0; ntp < 2; ++ntp) {
                const float h = htree(acc[ntp]);
                m[ntp] = hh ? fmaxf(m[ntp], h) : h;
            }
        }
        #pragma unroll
        for (int ntp = 0; ntp < 2; ++ntp) {
            m[ntp] = fmaxf(m[ntp], __shfl_down(m[ntp], 32));
            if (lane < 32)
                out[(base + 2 * q + pg) * HH + w4 * 64 + ntp * 32 + l5]
                    = m[ntp] + dm[q][ntp] + bias[ntp];
        }
    }
}

extern "C" void kernel_launch(void* const* d_in, const int* in_sizes, int n_in,
                              void* d_out, int out_size, void* d_ws, size_t ws_size,
                              hipStream_t stream) {
    const float* points  = (const float*)d_in[0];
    const float* anchors = (const float*)d_in[1];
    // d_in[2] = cor_score: unused by the reference
    const float* Wa = (const float*)d_in[3];
    const float* ba = (const float*)d_in[4];
    const float* Wd = (const float*)d_in[5];
    const float* bd = (const float*)d_in[6];

    unsigned short* wbf = (unsigned short*)d_ws;  // 112 KB: trimmed+aug Wd|Wa bf16

    hipLaunchKernelGGL(prep_w_kernel, dim3(8), dim3(64), 0, stream, Wa, Wd, wbf);
    hipLaunchKernelGGL(cgse_main, dim3(NPTS / P_PTS), dim3(512), 0, stream,
                       points, anchors, wbf, ba, bd, (float*)d_out);
}